// Round 16
// baseline (122.275 us; speedup 1.0000x reference)
//
#include <hip/hip_runtime.h>
#include <hip/hip_bf16.h>
#include <math.h>

typedef unsigned short u16;
typedef unsigned int   u32;
typedef unsigned long long u64;
typedef __attribute__((ext_vector_type(8))) short bf16x8;
typedef __attribute__((ext_vector_type(4))) short bf16x4;
typedef __attribute__((ext_vector_type(4))) float f32x4;

#define B_   2
#define S_   2048
#define HID_ 1024
#define NH_  16
#define HD_  64
#define MR_  (B_*S_)   // 4096 rows

// 0.125 * log2(e) : folds the 1/sqrt(64) score scale and exp->exp2 into Q.
#define QSCALE 0.1803368801111137f
// Static softmax bias (log2 domain); see round-9 analysis.
#define MBIAS 32.0f

__device__ __forceinline__ u16 f2bf(float f) {
  union { float f; u32 u; } x; x.f = f;
  u32 r = x.u + 0x7fffu + ((x.u >> 16) & 1u);
  return (u16)(r >> 16);
}
__device__ __forceinline__ void gload16(const void* g, void* l) {
  __builtin_amdgcn_global_load_lds(
      (const __attribute__((address_space(1))) u32*)g,
      (__attribute__((address_space(3))) u32*)l, 16, 0, 0);
}

// ---------------- fused f32 -> bf16 convert (hs + 4 weights) ----------------
__global__ void k_cvt_all(const float* __restrict__ hs, const float* __restrict__ wq,
                          const float* __restrict__ wk, const float* __restrict__ wv,
                          const float* __restrict__ wo, ushort4* __restrict__ dst) {
  int i = blockIdx.x * blockDim.x + threadIdx.x;   // < 2097152
  const float4* src;
  int idx;
  if (i < 1048576) {
    src = (const float4*)hs; idx = i;
  } else {
    int j = i - 1048576;
    int w = j >> 18; idx = j & 262143;
    src = (const float4*)(w == 0 ? wq : w == 1 ? wk : w == 2 ? wv : wo);
  }
  float4 v = src[idx];
  ushort4 o;
  o.x = f2bf(v.x); o.y = f2bf(v.y); o.z = f2bf(v.z); o.w = f2bf(v.w);
  dst[i] = o;
}

// ---------------- rope table (exact reference gather semantics) ----------------
__global__ void k_rope_table(float2* __restrict__ tab) {
  int t = blockIdx.x * blockDim.x + threadIdx.x;   // < 65536
  int p = t >> 5, j = t & 31;
  double fp = (double)p;
  double c, s;
  if (j < 16) {
    s = sin(fp * pow(10000.0, -(2.0 * j) / 32.0));
    c = sin(fp * pow(10000.0, -(2.0 * j + 1.0) / 32.0));
  } else {
    s = cos(fp * pow(10000.0, -(2.0 * j - 32.0) / 32.0));
    c = cos(fp * pow(10000.0, -(2.0 * j - 31.0) / 32.0));
  }
  tab[p * 32 + j] = make_float2((float)c, (float)s);
}

// ---------------- QKV GEMM: 128x128 tile, 8 waves, 3-slot rotating halves --
// TLP experiment (R15 post-mortem): every 128^2 variant used 64KB LDS =
// 2 blocks/CU; schedules didn't matter (48us across three). This cuts LDS
// to 48KB via a 3-slot rotating K-half buffer -> 3 blocks/CU (24 waves/CU).
// Half-step s (= tile s>>1, half s&1) lives in slot s%3. Phase s:
//   vmcnt(2)[group s landed; group s+1 in flight] -> barrier ->
//   issue stage of half s+2 into slot (s+2)%3 -> read frags -> 8 MFMA.
// Slot-rotation safety: slot (s+2)%3 was last READ in phase s-1; the
// phase-s barrier is after all waves finished phase s-1 (ds_reads retired
// before their MFMAs), so post-barrier writes are safe. vmcnt math: newer-
// than-target is always one 2-load group -> vmcnt(2); vmcnt(0) last phase.
// Swizzle: 64B rows (4 x 16B slots), slot ^ ((row>>1)&3), both sides
// (0 conflicts, rounds 12-14). Grid (24,32): 24===0 mod 8 keeps each
// n-column on one XCD.
__global__ __launch_bounds__(512) void k_qkv(
    const u16* __restrict__ A,
    const u16* __restrict__ W0, const u16* __restrict__ W1, const u16* __restrict__ W2,
    u16* __restrict__ O0, u16* __restrict__ O1, u16* __restrict__ O2,
    const float2* __restrict__ tab) {
  __shared__ __align__(16) u16 Alds[3][128 * 32];
  __shared__ __align__(16) u16 Blds[3][128 * 32];

  int tid = threadIdx.x;
  int lane = tid & 63, wave = tid >> 6;
  int m0 = blockIdx.y * 128;
  int nt0 = blockIdx.x * 128;
  int wi = nt0 >> 10;
  const u16* W = (wi == 0) ? W0 : (wi == 1 ? W1 : W2);
  int n0 = nt0 & 1023;
  int wm = wave >> 1, wn = wave & 1;
  int lg = lane >> 4, lr = lane & 15;

  f32x4 acc[2][4];
  const f32x4 vz = {0.f, 0.f, 0.f, 0.f};
#pragma unroll
  for (int i = 0; i < 2; ++i)
#pragma unroll
    for (int j = 0; j < 4; ++j) acc[i][j] = vz;

  // one 16B chunk per thread per group (512 chunks = 128 rows x 32 cols)
  auto SA = [&](int t_, int sl_, int hk_) {
    int row = tid >> 2, sl = tid & 3;
    int cw = sl ^ ((row >> 1) & 3);    // pre-swizzled source
    gload16(&A[(size_t)(m0 + row) * HID_ + t_ * 64 + hk_ * 32 + cw * 8],
            &Alds[sl_][(wave * 64) * 8]);
  };
  auto SB = [&](int t_, int sl_, int hk_) {
    int row = tid >> 2, sl = tid & 3;
    int cw = sl ^ ((row >> 1) & 3);
    gload16(&W[(size_t)(n0 + row) * HID_ + t_ * 64 + hk_ * 32 + cw * 8],
            &Blds[sl_][(wave * 64) * 8]);
  };

  // prologue: half-steps 0,1 into slots 0,1
  SA(0, 0, 0); SB(0, 0, 0);
  SA(0, 1, 1); SB(0, 1, 1);

#pragma unroll
  for (int s = 0; s < 32; ++s) {
    int slot = s % 3;
    if (s < 31) { asm volatile("s_waitcnt vmcnt(2)" ::: "memory"); }
    else        { asm volatile("s_waitcnt vmcnt(0)" ::: "memory"); }
    __builtin_amdgcn_s_barrier();
    __builtin_amdgcn_sched_barrier(0);
    if (s + 2 < 32) {
      int ns = s + 2;
      SA(ns >> 1, ns % 3, ns & 1);
      SB(ns >> 1, ns % 3, ns & 1);
    }

    bf16x8 bfr[4], afr[2];
#pragma unroll
    for (int ni = 0; ni < 4; ++ni) {
      int row = wn * 64 + ni * 16 + lr;
      int ci = lg ^ ((row >> 1) & 3);
      bfr[ni] = *(const bf16x8*)&Blds[slot][row * 32 + ci * 8];
    }
#pragma unroll
    for (int mi = 0; mi < 2; ++mi) {
      int row = wm * 32 + mi * 16 + lr;
      int ci = lg ^ ((row >> 1) & 3);
      afr[mi] = *(const bf16x8*)&Alds[slot][row * 32 + ci * 8];
    }
    __builtin_amdgcn_s_setprio(1);
#pragma unroll
    for (int mi = 0; mi < 2; ++mi)
#pragma unroll
      for (int ni = 0; ni < 4; ++ni)
        acc[mi][ni] = __builtin_amdgcn_mfma_f32_16x16x32_bf16(afr[mi], bfr[ni], acc[mi][ni], 0, 0, 0);
    __builtin_amdgcn_s_setprio(0);
  }

  // ---------------- epilogues (per-wave 32x64 at (wm*32, wn*64)) ----------
  if (wi == 2) {
    // V: write transposed vt[((b*16+h)*64 + d)*2048 + s], 4 rows packed per u64
#pragma unroll
    for (int mi = 0; mi < 2; ++mi) {
      int grow0 = m0 + wm * 32 + mi * 16 + lg * 4;
      int bb = grow0 >> 11;
      int s = grow0 & 2047;
#pragma unroll
      for (int ni = 0; ni < 4; ++ni) {
        int gcol = n0 + wn * 64 + ni * 16 + lr;
        int h = gcol >> 6, dd = gcol & 63;
        u64 pk = (u64)f2bf(acc[mi][ni][0]) |
                 ((u64)f2bf(acc[mi][ni][1]) << 16) |
                 ((u64)f2bf(acc[mi][ni][2]) << 32) |
                 ((u64)f2bf(acc[mi][ni][3]) << 48);
        *(u64*)&O2[((size_t)(bb * NH_ + h) * HD_ + dd) * S_ + s] = pk;
      }
    }
  } else {
    // Q / K: RoPE in-epilogue. Pair (2j, 2j+1) lives in lanes (lr even, lr odd).
    u16* OB = wi ? O1 : O0;
    float sc = wi ? 1.0f : QSCALE;
#pragma unroll
    for (int mi = 0; mi < 2; ++mi) {
#pragma unroll
      for (int ni = 0; ni < 4; ++ni) {
        int gcol = n0 + wn * 64 + ni * 16 + lr;
        int h = gcol >> 6;
        int j = (gcol & 63) >> 1;
        bool even = !(gcol & 1);
        int ocol = h * 64 + (even ? j : 32 + j);
#pragma unroll
        for (int r = 0; r < 4; ++r) {
          float val = acc[mi][ni][r];
          float pv = __shfl_xor(val, 1);
          int grow = m0 + wm * 32 + mi * 16 + lg * 4 + r;
          int s = grow & 2047;
          float2 cs = tab[s * 32 + j];
          float xe = even ? val : pv;
          float xo = even ? pv : val;
          float res = even ? (xe * cs.x - xo * cs.y) : (xe * cs.y + xo * cs.x);
          OB[(size_t)grow * 1024 + ocol] = f2bf(res * sc);
        }
      }
    }
  }
}

// ---------------- O-projection GEMM: 64x128 tile, 8 waves, 1-barrier dbuf --
__global__ __launch_bounds__(512) void k_oproj(
    const u16* __restrict__ A, const u16* __restrict__ W0,
    float* __restrict__ OF, int K) {
  __shared__ __align__(16) u16 Al[2][64 * 64];
  __shared__ __align__(16) u16 Bl[2][128 * 64];

  int tid = threadIdx.x;
  int lane = tid & 63, wave = tid >> 6;
  int m0 = blockIdx.y * 64;
  int n0 = blockIdx.x * 128;
  int wm = wave >> 1, wn = wave & 1;
  int lg = lane >> 4, lr = lane & 15;

  f32x4 acc[4];
  const f32x4 vz = {0.f, 0.f, 0.f, 0.f};
#pragma unroll
  for (int j = 0; j < 4; ++j) acc[j] = vz;

  auto STAGE = [&](int t_, int bs_) {
    int k0 = t_ * 64;
    {
      int c = tid;
      int row = c >> 3;
      int cw = (c & 7) ^ (row & 7);
      gload16(&A[(size_t)(m0 + row) * K + k0 + cw * 8], &Al[bs_][(wave * 64) * 8]);
    }
#pragma unroll
    for (int it = 0; it < 2; ++it) {
      int c = it * 512 + tid;
      int row = c >> 3;
      int cw = (c & 7) ^ (row & 7);
      gload16(&W0[(size_t)(n0 + row) * K + k0 + cw * 8], &Bl[bs_][(it * 512 + wave * 64) * 8]);
    }
  };

  int nkt = K >> 6;
  STAGE(0, 0);

  for (int t = 0; t < nkt; ++t) {
    int cur = t & 1;
    asm volatile("s_waitcnt vmcnt(0)" ::: "memory");
    __builtin_amdgcn_s_barrier();
    __builtin_amdgcn_sched_barrier(0);
    if (t + 1 < nkt) STAGE(t + 1, cur ^ 1);

#pragma unroll
    for (int kk = 0; kk < 2; ++kk) {
      bf16x8 af, bfr[4];
      {
        int row = wm * 16 + lr;
        int ci = (kk * 4 + lg) ^ (row & 7);
        af = *(const bf16x8*)&Al[cur][row * 64 + ci * 8];
      }
#pragma unroll
      for (int ni = 0; ni < 4; ++ni) {
        int row = wn * 64 + ni * 16 + lr;
        int ci = (kk * 4 + lg) ^ (row & 7);
        bfr[ni] = *(const bf16x8*)&Bl[cur][row * 64 + ci * 8];
      }
      __builtin_amdgcn_s_setprio(1);
#pragma unroll
      for (int ni = 0; ni < 4; ++ni)
        acc[ni] = __builtin_amdgcn_mfma_f32_16x16x32_bf16(af, bfr[ni], acc[ni], 0, 0, 0);
      __builtin_amdgcn_s_setprio(0);
    }
  }

#pragma unroll
  for (int ni = 0; ni < 4; ++ni)
#pragma unroll
    for (int r = 0; r < 4; ++r) {
      int grow = m0 + wm * 16 + lg * 4 + r;
      int gcol = n0 + wn * 64 + ni * 16 + lr;
      OF[(size_t)grow * 1024 + gcol] = acc[ni][r];
    }
}

// ---------------- flash attention v6 (round-11 proven, 115.05 config) ------
__global__ __launch_bounds__(256, 4) void k_attn(
    const u16* __restrict__ Q, const u16* __restrict__ Kr, const u16* __restrict__ VT,
    u16* __restrict__ O) {
  __shared__ __align__(16) u16 Kl[2][64 * 64];
  __shared__ __align__(16) u16 Vl[2][64 * 64];

  int tid = threadIdx.x, lane = tid & 63, wave = tid >> 6;
  int id = blockIdx.x;                 // 0..1023
  int qt = 31 - (id >> 5);             // descending work (LPT)
  int bh = id & 31;
  int b = bh >> 4, h = bh & 15;
  int lg = lane >> 4, lr = lane & 15;
  int bS = b * S_;
  int nkt = qt + 1;
  int q0 = qt * 64 + wave * 16;

  const u16* vtb = &VT[(size_t)bh * HD_ * S_];
  int l8 = lane >> 3, l7 = lane & 7;
  int sl = l7 ^ l8;   // pre-swizzled global slot

  auto STAGE = [&](int kt_, int bs_) {
#pragma unroll
    for (int it = 0; it < 2; ++it) {
      int rb = wave * 16 + it * 8;     // wave-uniform LDS row base
      int r = rb + l8;
      gload16(&Kr[(size_t)(bS + kt_ * 64 + r) * HID_ + h * HD_ + sl * 8],
              &Kl[bs_][rb * 64]);
      gload16(&vtb[(size_t)r * S_ + kt_ * 64 + sl * 8],
              &Vl[bs_][rb * 64]);
    }
  };

  STAGE(0, 0);

  bf16x8 qf[2];
#pragma unroll
  for (int kk = 0; kk < 2; ++kk)
    qf[kk] = *(const bf16x8*)
        &Q[(size_t)(bS + q0 + lr) * HID_ + h * HD_ + kk * 32 + lg * 8];

  f32x4 acc[4];
  const f32x4 vz = {0.f, 0.f, 0.f, 0.f};
#pragma unroll
  for (int df = 0; df < 4; ++df) acc[df] = vz;
  float l_ = 0.f;                      // per-lane partial sum

  for (int kt = 0; kt < nkt; ++kt) {
    int cur = kt & 1;
    if (kt + 1 < nkt) {
      STAGE(kt + 1, cur ^ 1);
      asm volatile("s_waitcnt vmcnt(4)" ::: "memory");
    } else {
      asm volatile("s_waitcnt vmcnt(0)" ::: "memory");
    }
    __builtin_amdgcn_s_barrier();
    __builtin_amdgcn_sched_barrier(0);

    // K fragments
    bf16x8 kfr[4][2];
#pragma unroll
    for (int kf = 0; kf < 4; ++kf) {
      int row = kf * 16 + lr;
#pragma unroll
      for (int kk = 0; kk < 2; ++kk) {
        int ci = (kk * 4 + lg) ^ (row & 7);
        kfr[kf][kk] = *(const bf16x8*)&Kl[cur][row * 64 + ci * 8];
      }
    }

    // QK^T (swapped): st rows = keys, cols = q
    f32x4 st[4];
#pragma unroll
    for (int kf = 0; kf < 4; ++kf) st[kf] = vz;
    __builtin_amdgcn_s_setprio(1);
#pragma unroll
    for (int kk = 0; kk < 2; ++kk)
#pragma unroll
      for (int kf = 0; kf < 4; ++kf)
        st[kf] = __builtin_amdgcn_mfma_f32_16x16x32_bf16(
            kfr[kf][kk], qf[kk], st[kf], 0, 0, 0);
    __builtin_amdgcn_s_setprio(0);

    if (kt == qt) {   // diagonal tile: causal mask
      int qg = q0 + lr;
#pragma unroll
      for (int kf = 0; kf < 4; ++kf)
#pragma unroll
        for (int r = 0; r < 4; ++r) {
          int kg = kt * 64 + kf * 16 + lg * 4 + r;
          if (kg > qg) st[kf][r] = -1e30f;
        }
    }

    // static-max softmax: P = exp2(st - MBIAS); no reductions, no rescale
    float ts = 0.f;
    bf16x4 pb[4];
#pragma unroll
    for (int kf = 0; kf < 4; ++kf) {
#pragma unroll
      for (int r = 0; r < 4; ++r) {
        float e = __builtin_amdgcn_exp2f(st[kf][r] - MBIAS);
        st[kf][r] = e;
        ts += e;
      }
      u32 w0, w1;
      asm("v_cvt_pk_bf16_f32 %0, %1, %2" : "=v"(w0) : "v"(st[kf][0]), "v"(st[kf][1]));
      asm("v_cvt_pk_bf16_f32 %0, %1, %2" : "=v"(w1) : "v"(st[kf][2]), "v"(st[kf][3]));
      union { u32 u[2]; bf16x4 v; } pk;
      pk.u[0] = w0; pk.u[1] = w1;
      pb[kf] = pk.v;
    }
    l_ += ts;

    // PV: O^T += V^T . P^T
    __builtin_amdgcn_s_setprio(1);
#pragma unroll
    for (int df = 0; df < 4; ++df) {
      int row = df * 16 + lr;
#pragma unroll
      for (int kf = 0; kf < 4; ++kf) {
        int slot = (kf * 2 + (lg >> 1)) ^ (row & 7);
        bf16x4 vfr = *(const bf16x4*)&Vl[cur][row * 64 + slot * 8 + (lg & 1) * 4];
        acc[df] = __builtin_amdgcn_mfma_f32_16x16x16bf16_1k(
            vfr, pb[kf], acc[df], 0, 0, 0);
      }
    }
    __builtin_amdgcn_s_setprio(0);

    __builtin_amdgcn_sched_barrier(0);
    __builtin_amdgcn_s_barrier();
  }

  // epilogue: reduce l across the 4 lane-groups once, then O = acc / l
  l_ += __shfl_xor(l_, 16);
  l_ += __shfl_xor(l_, 32);
  float inv = 1.0f / l_;
  int grow = bS + q0 + lr;
#pragma unroll
  for (int df = 0; df < 4; ++df) {
    u64 pk = (u64)f2bf(acc[df][0] * inv) |
             ((u64)f2bf(acc[df][1] * inv) << 16) |
             ((u64)f2bf(acc[df][2] * inv) << 32) |
             ((u64)f2bf(acc[df][3] * inv) << 48);
    *(u64*)&O[(size_t)grow * HID_ + h * HD_ + df * 16 + lg * 4] = pk;
  }
}

// ---------------- launch ----------------
extern "C" void kernel_launch(void* const* d_in, const int* in_sizes, int n_in,
                              void* d_out, int out_size, void* d_ws, size_t ws_size,
                              hipStream_t stream) {
  const float* hs = (const float*)d_in[0];
  const float* wq = (const float*)d_in[2];
  const float* wk = (const float*)d_in[3];
  const float* wv = (const float*)d_in[4];
  const float* wo = (const float*)d_in[5];
  float* out = (float*)d_out;

  char* ws = (char*)d_ws;
  const size_t P = (size_t)MR_ * HID_ * 2;   // 8 MiB plane
  u16* Xb  = (u16*)(ws);                     // plane 0; reused as attn_o
  u16* Wqb = (u16*)(ws + P);
  u16* Wkb = (u16*)(ws + P + (size_t)HID_ * HID_ * 2);
  u16* Wvb = (u16*)(ws + P + (size_t)HID_ * HID_ * 4);
  u16* Wob = (u16*)(ws + P + (size_t)HID_ * HID_ * 6);
  u16* q_r = (u16*)(ws + 2 * P);
  u16* k_r = (u16*)(ws + 3 * P);
  u16* vt  = (u16*)(ws + 4 * P);
  float2* tab = (float2*)(ws + 5 * P);
  u16* attn_o = Xb;

  // converts + rope table
  k_cvt_all<<<8192, 256, 0, stream>>>(hs, wq, wk, wv, wo, (ushort4*)ws);
  k_rope_table<<<256, 256, 0, stream>>>(tab);

  // QKV projections (128^2, 8 waves, 3-slot rotating K-halves, 48KB LDS)
  k_qkv<<<dim3(24, 32), 512, 0, stream>>>(
      Xb, Wqb, Wkb, Wvb, q_r, k_r, vt, tab);

  // attention (LPT-ordered triangular blocks, static-max softmax)
  k_attn<<<1024, 256, 0, stream>>>(q_r, k_r, vt, attn_o);

  // output projection -> f32
  k_oproj<<<dim3(8, 64), 512, 0, stream>>>(attn_o, Wob, out, HID_);
}

// Round 17
// 114.508 us; speedup vs baseline: 1.0678x; 1.0678x over previous
//
#include <hip/hip_runtime.h>
#include <hip/hip_bf16.h>
#include <math.h>

typedef unsigned short u16;
typedef unsigned int   u32;
typedef unsigned long long u64;
typedef __attribute__((ext_vector_type(8))) short bf16x8;
typedef __attribute__((ext_vector_type(4))) short bf16x4;
typedef __attribute__((ext_vector_type(4))) float f32x4;

#define B_   2
#define S_   2048
#define HID_ 1024
#define NH_  16
#define HD_  64
#define MR_  (B_*S_)   // 4096 rows

// 0.125 * log2(e) : folds the 1/sqrt(64) score scale and exp->exp2 into Q.
#define QSCALE 0.1803368801111137f
// Static softmax bias (log2 domain); see round-9 analysis.
#define MBIAS 32.0f

__device__ __forceinline__ u16 f2bf(float f) {
  union { float f; u32 u; } x; x.f = f;
  u32 r = x.u + 0x7fffu + ((x.u >> 16) & 1u);
  return (u16)(r >> 16);
}
__device__ __forceinline__ void gload16(const void* g, void* l) {
  __builtin_amdgcn_global_load_lds(
      (const __attribute__((address_space(1))) u32*)g,
      (__attribute__((address_space(3))) u32*)l, 16, 0, 0);
}

// ---------------- fused f32 -> bf16 convert (hs + 4 weights) ----------------
__global__ void k_cvt_all(const float* __restrict__ hs, const float* __restrict__ wq,
                          const float* __restrict__ wk, const float* __restrict__ wv,
                          const float* __restrict__ wo, ushort4* __restrict__ dst) {
  int i = blockIdx.x * blockDim.x + threadIdx.x;   // < 2097152
  const float4* src;
  int idx;
  if (i < 1048576) {
    src = (const float4*)hs; idx = i;
  } else {
    int j = i - 1048576;
    int w = j >> 18; idx = j & 262143;
    src = (const float4*)(w == 0 ? wq : w == 1 ? wk : w == 2 ? wv : wo);
  }
  float4 v = src[idx];
  ushort4 o;
  o.x = f2bf(v.x); o.y = f2bf(v.y); o.z = f2bf(v.z); o.w = f2bf(v.w);
  dst[i] = o;
}

// ---------------- rope table (exact reference gather semantics) ----------------
__global__ void k_rope_table(float2* __restrict__ tab) {
  int t = blockIdx.x * blockDim.x + threadIdx.x;   // < 65536
  int p = t >> 5, j = t & 31;
  double fp = (double)p;
  double c, s;
  if (j < 16) {
    s = sin(fp * pow(10000.0, -(2.0 * j) / 32.0));
    c = sin(fp * pow(10000.0, -(2.0 * j + 1.0) / 32.0));
  } else {
    s = cos(fp * pow(10000.0, -(2.0 * j - 32.0) / 32.0));
    c = cos(fp * pow(10000.0, -(2.0 * j - 31.0) / 32.0));
  }
  tab[p * 32 + j] = make_float2((float)c, (float)s);
}

// ---------------- QKV GEMM: 128x128 tile, 8 waves, K-half counted-vmcnt ----
// (Round-14 proven best: 48.0 us.) Wave grid 4(M)x2(N); per-wave 32x64
// (acc[2][4]). LDS 64KB: A/B each split into K-halves, double-buffered ->
// 2 blocks/CU. Per K-tile t, 2 phases (8 MFMA each); stage groups
// G1=[A.K0,B.K0], G2=[A.K1,B.K1], 2 loads/thread each:
//  Ph1: vmcnt(2)[G1(t) landed, G2(t) in flight] bar | issue G1(t+1)
//       | read half0 frags | 8 MFMA
//  Ph2: vmcnt(2)[G2(t) landed, G1(t+1) in flight] bar | issue G2(t+1)
//       | read half1 frags | 8 MFMA
// Loads never drain mid-loop (vmcnt(0) only at the final Ph2). Swizzle:
// 64B rows (4 x 16B slots), slot ^ ((row>>1)&3), both sides (0 conflicts).
// Grid (24,32): 24===0 mod 8 keeps each n-column on one XCD.
__global__ __launch_bounds__(512) void k_qkv(
    const u16* __restrict__ A,
    const u16* __restrict__ W0, const u16* __restrict__ W1, const u16* __restrict__ W2,
    u16* __restrict__ O0, u16* __restrict__ O1, u16* __restrict__ O2,
    const float2* __restrict__ tab) {
  __shared__ __align__(16) u16 Alds[2][2][128 * 32];
  __shared__ __align__(16) u16 Blds[2][2][128 * 32];

  int tid = threadIdx.x;
  int lane = tid & 63, wave = tid >> 6;
  int m0 = blockIdx.y * 128;
  int nt0 = blockIdx.x * 128;
  int wi = nt0 >> 10;
  const u16* W = (wi == 0) ? W0 : (wi == 1 ? W1 : W2);
  int n0 = nt0 & 1023;
  int wm = wave >> 1, wn = wave & 1;
  int lg = lane >> 4, lr = lane & 15;

  f32x4 acc[2][4];
  const f32x4 vz = {0.f, 0.f, 0.f, 0.f};
#pragma unroll
  for (int i = 0; i < 2; ++i)
#pragma unroll
    for (int j = 0; j < 4; ++j) acc[i][j] = vz;

  // one 16B chunk per thread per group (512 chunks cover 128 rows x 32 cols)
  auto SA = [&](int t_, int d_, int hk_) {
    int row = tid >> 2, sl = tid & 3;
    int cw = sl ^ ((row >> 1) & 3);    // pre-swizzled source
    gload16(&A[(size_t)(m0 + row) * HID_ + t_ * 64 + hk_ * 32 + cw * 8],
            &Alds[d_][hk_][(wave * 64) * 8]);
  };
  auto SB = [&](int t_, int d_, int hk_) {
    int row = tid >> 2, sl = tid & 3;
    int cw = sl ^ ((row >> 1) & 3);
    gload16(&W[(size_t)(n0 + row) * HID_ + t_ * 64 + hk_ * 32 + cw * 8],
            &Blds[d_][hk_][(wave * 64) * 8]);
  };

  // prologue: tile 0, groups in order G1=[AK0,BK0], G2=[AK1,BK1]
  SA(0, 0, 0); SB(0, 0, 0); SA(0, 0, 1); SB(0, 0, 1);

  for (int t = 0; t < 16; ++t) {
    int cur = t & 1, nxt = cur ^ 1;
    bool more = (t < 15);
    bf16x8 bfr[4], afr[2];

    // ---------------- Ph1 (K-half 0) ----------------
    asm volatile("s_waitcnt vmcnt(2)" ::: "memory");
    __builtin_amdgcn_s_barrier();
    __builtin_amdgcn_sched_barrier(0);
    if (more) { SA(t + 1, nxt, 0); SB(t + 1, nxt, 0); }
#pragma unroll
    for (int ni = 0; ni < 4; ++ni) {
      int row = wn * 64 + ni * 16 + lr;
      int ci = lg ^ ((row >> 1) & 3);
      bfr[ni] = *(const bf16x8*)&Blds[cur][0][row * 32 + ci * 8];
    }
#pragma unroll
    for (int mi = 0; mi < 2; ++mi) {
      int row = wm * 32 + mi * 16 + lr;
      int ci = lg ^ ((row >> 1) & 3);
      afr[mi] = *(const bf16x8*)&Alds[cur][0][row * 32 + ci * 8];
    }
    __builtin_amdgcn_s_setprio(1);
#pragma unroll
    for (int mi = 0; mi < 2; ++mi)
#pragma unroll
      for (int ni = 0; ni < 4; ++ni)
        acc[mi][ni] = __builtin_amdgcn_mfma_f32_16x16x32_bf16(afr[mi], bfr[ni], acc[mi][ni], 0, 0, 0);
    __builtin_amdgcn_s_setprio(0);

    // ---------------- Ph2 (K-half 1) ----------------
    if (more) { asm volatile("s_waitcnt vmcnt(2)" ::: "memory"); }
    else      { asm volatile("s_waitcnt vmcnt(0)" ::: "memory"); }
    __builtin_amdgcn_s_barrier();
    __builtin_amdgcn_sched_barrier(0);
    if (more) { SA(t + 1, nxt, 1); SB(t + 1, nxt, 1); }
#pragma unroll
    for (int ni = 0; ni < 4; ++ni) {
      int row = wn * 64 + ni * 16 + lr;
      int ci = lg ^ ((row >> 1) & 3);
      bfr[ni] = *(const bf16x8*)&Blds[cur][1][row * 32 + ci * 8];
    }
#pragma unroll
    for (int mi = 0; mi < 2; ++mi) {
      int row = wm * 32 + mi * 16 + lr;
      int ci = lg ^ ((row >> 1) & 3);
      afr[mi] = *(const bf16x8*)&Alds[cur][1][row * 32 + ci * 8];
    }
    __builtin_amdgcn_s_setprio(1);
#pragma unroll
    for (int mi = 0; mi < 2; ++mi)
#pragma unroll
      for (int ni = 0; ni < 4; ++ni)
        acc[mi][ni] = __builtin_amdgcn_mfma_f32_16x16x32_bf16(afr[mi], bfr[ni], acc[mi][ni], 0, 0, 0);
    __builtin_amdgcn_s_setprio(0);
  }

  // ---------------- epilogues (per-wave 32x64 at (wm*32, wn*64)) ----------
  if (wi == 2) {
    // V: write transposed vt[((b*16+h)*64 + d)*2048 + s], 4 rows packed per u64
#pragma unroll
    for (int mi = 0; mi < 2; ++mi) {
      int grow0 = m0 + wm * 32 + mi * 16 + lg * 4;
      int bb = grow0 >> 11;
      int s = grow0 & 2047;
#pragma unroll
      for (int ni = 0; ni < 4; ++ni) {
        int gcol = n0 + wn * 64 + ni * 16 + lr;
        int h = gcol >> 6, dd = gcol & 63;
        u64 pk = (u64)f2bf(acc[mi][ni][0]) |
                 ((u64)f2bf(acc[mi][ni][1]) << 16) |
                 ((u64)f2bf(acc[mi][ni][2]) << 32) |
                 ((u64)f2bf(acc[mi][ni][3]) << 48);
        *(u64*)&O2[((size_t)(bb * NH_ + h) * HD_ + dd) * S_ + s] = pk;
      }
    }
  } else {
    // Q / K: RoPE in-epilogue. Pair (2j, 2j+1) lives in lanes (lr even, lr odd).
    u16* OB = wi ? O1 : O0;
    float sc = wi ? 1.0f : QSCALE;
#pragma unroll
    for (int mi = 0; mi < 2; ++mi) {
#pragma unroll
      for (int ni = 0; ni < 4; ++ni) {
        int gcol = n0 + wn * 64 + ni * 16 + lr;
        int h = gcol >> 6;
        int j = (gcol & 63) >> 1;
        bool even = !(gcol & 1);
        int ocol = h * 64 + (even ? j : 32 + j);
#pragma unroll
        for (int r = 0; r < 4; ++r) {
          float val = acc[mi][ni][r];
          float pv = __shfl_xor(val, 1);
          int grow = m0 + wm * 32 + mi * 16 + lg * 4 + r;
          int s = grow & 2047;
          float2 cs = tab[s * 32 + j];
          float xe = even ? val : pv;
          float xo = even ? pv : val;
          float res = even ? (xe * cs.x - xo * cs.y) : (xe * cs.y + xo * cs.x);
          OB[(size_t)grow * 1024 + ocol] = f2bf(res * sc);
        }
      }
    }
  }
}

// ---------------- O-projection GEMM: 64x128 tile, 8 waves, 1-barrier dbuf --
__global__ __launch_bounds__(512) void k_oproj(
    const u16* __restrict__ A, const u16* __restrict__ W0,
    float* __restrict__ OF, int K) {
  __shared__ __align__(16) u16 Al[2][64 * 64];
  __shared__ __align__(16) u16 Bl[2][128 * 64];

  int tid = threadIdx.x;
  int lane = tid & 63, wave = tid >> 6;
  int m0 = blockIdx.y * 64;
  int n0 = blockIdx.x * 128;
  int wm = wave >> 1, wn = wave & 1;
  int lg = lane >> 4, lr = lane & 15;

  f32x4 acc[4];
  const f32x4 vz = {0.f, 0.f, 0.f, 0.f};
#pragma unroll
  for (int j = 0; j < 4; ++j) acc[j] = vz;

  auto STAGE = [&](int t_, int bs_) {
    int k0 = t_ * 64;
    {
      int c = tid;
      int row = c >> 3;
      int cw = (c & 7) ^ (row & 7);
      gload16(&A[(size_t)(m0 + row) * K + k0 + cw * 8], &Al[bs_][(wave * 64) * 8]);
    }
#pragma unroll
    for (int it = 0; it < 2; ++it) {
      int c = it * 512 + tid;
      int row = c >> 3;
      int cw = (c & 7) ^ (row & 7);
      gload16(&W0[(size_t)(n0 + row) * K + k0 + cw * 8], &Bl[bs_][(it * 512 + wave * 64) * 8]);
    }
  };

  int nkt = K >> 6;
  STAGE(0, 0);

  for (int t = 0; t < nkt; ++t) {
    int cur = t & 1;
    asm volatile("s_waitcnt vmcnt(0)" ::: "memory");
    __builtin_amdgcn_s_barrier();
    __builtin_amdgcn_sched_barrier(0);
    if (t + 1 < nkt) STAGE(t + 1, cur ^ 1);

#pragma unroll
    for (int kk = 0; kk < 2; ++kk) {
      bf16x8 af, bfr[4];
      {
        int row = wm * 16 + lr;
        int ci = (kk * 4 + lg) ^ (row & 7);
        af = *(const bf16x8*)&Al[cur][row * 64 + ci * 8];
      }
#pragma unroll
      for (int ni = 0; ni < 4; ++ni) {
        int row = wn * 64 + ni * 16 + lr;
        int ci = (kk * 4 + lg) ^ (row & 7);
        bfr[ni] = *(const bf16x8*)&Bl[cur][row * 64 + ci * 8];
      }
      __builtin_amdgcn_s_setprio(1);
#pragma unroll
      for (int ni = 0; ni < 4; ++ni)
        acc[ni] = __builtin_amdgcn_mfma_f32_16x16x32_bf16(af, bfr[ni], acc[ni], 0, 0, 0);
      __builtin_amdgcn_s_setprio(0);
    }
  }

#pragma unroll
  for (int ni = 0; ni < 4; ++ni)
#pragma unroll
    for (int r = 0; r < 4; ++r) {
      int grow = m0 + wm * 16 + lg * 4 + r;
      int gcol = n0 + wn * 64 + ni * 16 + lr;
      OF[(size_t)grow * 1024 + gcol] = acc[ni][r];
    }
}

// ---------------- flash attention v6 (round-14 proven) ---------------------
// One 64-row q-tile per block (4 waves x 16 rows), KVBLK=64, dbuf, counted
// vmcnt, grid 1024 LPT, 4 blocks/CU; static-max softmax; per-lane partial l
// reduced once in the epilogue.
__global__ __launch_bounds__(256, 4) void k_attn(
    const u16* __restrict__ Q, const u16* __restrict__ Kr, const u16* __restrict__ VT,
    u16* __restrict__ O) {
  __shared__ __align__(16) u16 Kl[2][64 * 64];
  __shared__ __align__(16) u16 Vl[2][64 * 64];

  int tid = threadIdx.x, lane = tid & 63, wave = tid >> 6;
  int id = blockIdx.x;                 // 0..1023
  int qt = 31 - (id >> 5);             // descending work (LPT)
  int bh = id & 31;
  int b = bh >> 4, h = bh & 15;
  int lg = lane >> 4, lr = lane & 15;
  int bS = b * S_;
  int nkt = qt + 1;
  int q0 = qt * 64 + wave * 16;

  const u16* vtb = &VT[(size_t)bh * HD_ * S_];
  int l8 = lane >> 3, l7 = lane & 7;
  int sl = l7 ^ l8;   // pre-swizzled global slot

  auto STAGE = [&](int kt_, int bs_) {
#pragma unroll
    for (int it = 0; it < 2; ++it) {
      int rb = wave * 16 + it * 8;     // wave-uniform LDS row base
      int r = rb + l8;
      gload16(&Kr[(size_t)(bS + kt_ * 64 + r) * HID_ + h * HD_ + sl * 8],
              &Kl[bs_][rb * 64]);
      gload16(&vtb[(size_t)r * S_ + kt_ * 64 + sl * 8],
              &Vl[bs_][rb * 64]);
    }
  };

  STAGE(0, 0);

  bf16x8 qf[2];
#pragma unroll
  for (int kk = 0; kk < 2; ++kk)
    qf[kk] = *(const bf16x8*)
        &Q[(size_t)(bS + q0 + lr) * HID_ + h * HD_ + kk * 32 + lg * 8];

  f32x4 acc[4];
  const f32x4 vz = {0.f, 0.f, 0.f, 0.f};
#pragma unroll
  for (int df = 0; df < 4; ++df) acc[df] = vz;
  float l_ = 0.f;                      // per-lane partial sum

  for (int kt = 0; kt < nkt; ++kt) {
    int cur = kt & 1;
    if (kt + 1 < nkt) {
      STAGE(kt + 1, cur ^ 1);
      asm volatile("s_waitcnt vmcnt(4)" ::: "memory");
    } else {
      asm volatile("s_waitcnt vmcnt(0)" ::: "memory");
    }
    __builtin_amdgcn_s_barrier();
    __builtin_amdgcn_sched_barrier(0);

    // K fragments
    bf16x8 kfr[4][2];
#pragma unroll
    for (int kf = 0; kf < 4; ++kf) {
      int row = kf * 16 + lr;
#pragma unroll
      for (int kk = 0; kk < 2; ++kk) {
        int ci = (kk * 4 + lg) ^ (row & 7);
        kfr[kf][kk] = *(const bf16x8*)&Kl[cur][row * 64 + ci * 8];
      }
    }

    // QK^T (swapped): st rows = keys, cols = q
    f32x4 st[4];
#pragma unroll
    for (int kf = 0; kf < 4; ++kf) st[kf] = vz;
    __builtin_amdgcn_s_setprio(1);
#pragma unroll
    for (int kk = 0; kk < 2; ++kk)
#pragma unroll
      for (int kf = 0; kf < 4; ++kf)
        st[kf] = __builtin_amdgcn_mfma_f32_16x16x32_bf16(
            kfr[kf][kk], qf[kk], st[kf], 0, 0, 0);
    __builtin_amdgcn_s_setprio(0);

    if (kt == qt) {   // diagonal tile: causal mask
      int qg = q0 + lr;
#pragma unroll
      for (int kf = 0; kf < 4; ++kf)
#pragma unroll
        for (int r = 0; r < 4; ++r) {
          int kg = kt * 64 + kf * 16 + lg * 4 + r;
          if (kg > qg) st[kf][r] = -1e30f;
        }
    }

    // static-max softmax: P = exp2(st - MBIAS); no reductions, no rescale
    float ts = 0.f;
    bf16x4 pb[4];
#pragma unroll
    for (int kf = 0; kf < 4; ++kf) {
#pragma unroll
      for (int r = 0; r < 4; ++r) {
        float e = __builtin_amdgcn_exp2f(st[kf][r] - MBIAS);
        st[kf][r] = e;
        ts += e;
      }
      u32 w0, w1;
      asm("v_cvt_pk_bf16_f32 %0, %1, %2" : "=v"(w0) : "v"(st[kf][0]), "v"(st[kf][1]));
      asm("v_cvt_pk_bf16_f32 %0, %1, %2" : "=v"(w1) : "v"(st[kf][2]), "v"(st[kf][3]));
      union { u32 u[2]; bf16x4 v; } pk;
      pk.u[0] = w0; pk.u[1] = w1;
      pb[kf] = pk.v;
    }
    l_ += ts;

    // PV: O^T += V^T . P^T
    __builtin_amdgcn_s_setprio(1);
#pragma unroll
    for (int df = 0; df < 4; ++df) {
      int row = df * 16 + lr;
#pragma unroll
      for (int kf = 0; kf < 4; ++kf) {
        int slot = (kf * 2 + (lg >> 1)) ^ (row & 7);
        bf16x4 vfr = *(const bf16x4*)&Vl[cur][row * 64 + slot * 8 + (lg & 1) * 4];
        acc[df] = __builtin_amdgcn_mfma_f32_16x16x16bf16_1k(
            vfr, pb[kf], acc[df], 0, 0, 0);
      }
    }
    __builtin_amdgcn_s_setprio(0);

    __builtin_amdgcn_sched_barrier(0);
    __builtin_amdgcn_s_barrier();
  }

  // epilogue: reduce l across the 4 lane-groups once, then O = acc / l
  l_ += __shfl_xor(l_, 16);
  l_ += __shfl_xor(l_, 32);
  float inv = 1.0f / l_;
  int grow = bS + q0 + lr;
#pragma unroll
  for (int df = 0; df < 4; ++df) {
    u64 pk = (u64)f2bf(acc[df][0] * inv) |
             ((u64)f2bf(acc[df][1] * inv) << 16) |
             ((u64)f2bf(acc[df][2] * inv) << 32) |
             ((u64)f2bf(acc[df][3] * inv) << 48);
    *(u64*)&O[(size_t)grow * HID_ + h * HD_ + df * 16 + lg * 4] = pk;
  }
}

// ---------------- launch ----------------
extern "C" void kernel_launch(void* const* d_in, const int* in_sizes, int n_in,
                              void* d_out, int out_size, void* d_ws, size_t ws_size,
                              hipStream_t stream) {
  const float* hs = (const float*)d_in[0];
  const float* wq = (const float*)d_in[2];
  const float* wk = (const float*)d_in[3];
  const float* wv = (const float*)d_in[4];
  const float* wo = (const float*)d_in[5];
  float* out = (float*)d_out;

  char* ws = (char*)d_ws;
  const size_t P = (size_t)MR_ * HID_ * 2;   // 8 MiB plane
  u16* Xb  = (u16*)(ws);                     // plane 0; reused as attn_o
  u16* Wqb = (u16*)(ws + P);
  u16* Wkb = (u16*)(ws + P + (size_t)HID_ * HID_ * 2);
  u16* Wvb = (u16*)(ws + P + (size_t)HID_ * HID_ * 4);
  u16* Wob = (u16*)(ws + P + (size_t)HID_ * HID_ * 6);
  u16* q_r = (u16*)(ws + 2 * P);
  u16* k_r = (u16*)(ws + 3 * P);
  u16* vt  = (u16*)(ws + 4 * P);
  float2* tab = (float2*)(ws + 5 * P);
  u16* attn_o = Xb;

  // converts + rope table
  k_cvt_all<<<8192, 256, 0, stream>>>(hs, wq, wk, wv, wo, (ushort4*)ws);
  k_rope_table<<<256, 256, 0, stream>>>(tab);

  // QKV projections (128^2, 8 waves, K-half counted-vmcnt) + fused epilogues
  k_qkv<<<dim3(24, 32), 512, 0, stream>>>(
      Xb, Wqb, Wkb, Wvb, q_r, k_r, vt, tab);

  // attention (LPT-ordered triangular blocks, static-max softmax)
  k_attn<<<1024, 256, 0, stream>>>(q_r, k_r, vt, attn_o);

  // output projection -> f32
  k_oproj<<<dim3(8, 64), 512, 0, stream>>>(attn_o, Wob, out, HID_);
}

// Round 18
// 111.516 us; speedup vs baseline: 1.0965x; 1.0268x over previous
//
#include <hip/hip_runtime.h>
#include <hip/hip_bf16.h>
#include <math.h>

typedef unsigned short u16;
typedef unsigned int   u32;
typedef unsigned long long u64;
typedef __attribute__((ext_vector_type(8))) short bf16x8;
typedef __attribute__((ext_vector_type(4))) short bf16x4;
typedef __attribute__((ext_vector_type(4))) float f32x4;

#define B_   2
#define S_   2048
#define HID_ 1024
#define NH_  16
#define HD_  64
#define MR_  (B_*S_)   // 4096 rows

// 0.125 * log2(e) : folds the 1/sqrt(64) score scale and exp->exp2 into Q.
#define QSCALE 0.1803368801111137f
// Static softmax bias (log2 domain); see round-9 analysis.
#define MBIAS 32.0f

__device__ __forceinline__ u16 f2bf(float f) {
  union { float f; u32 u; } x; x.f = f;
  u32 r = x.u + 0x7fffu + ((x.u >> 16) & 1u);
  return (u16)(r >> 16);
}
__device__ __forceinline__ void gload16(const void* g, void* l) {
  __builtin_amdgcn_global_load_lds(
      (const __attribute__((address_space(1))) u32*)g,
      (__attribute__((address_space(3))) u32*)l, 16, 0, 0);
}

// ---------------- fused f32 -> bf16 convert (hs + 4 weights) ----------------
// NOTE: weights land CONTIGUOUSLY at ws+P: [wq(1024) | wk(1024) | wv(1024) |
// wo(1024)] rows -> k_qkv treats rows 0..3071 as one concatenated B matrix.
__global__ void k_cvt_all(const float* __restrict__ hs, const float* __restrict__ wq,
                          const float* __restrict__ wk, const float* __restrict__ wv,
                          const float* __restrict__ wo, ushort4* __restrict__ dst) {
  int i = blockIdx.x * blockDim.x + threadIdx.x;   // < 2097152
  const float4* src;
  int idx;
  if (i < 1048576) {
    src = (const float4*)hs; idx = i;
  } else {
    int j = i - 1048576;
    int w = j >> 18; idx = j & 262143;
    src = (const float4*)(w == 0 ? wq : w == 1 ? wk : w == 2 ? wv : wo);
  }
  float4 v = src[idx];
  ushort4 o;
  o.x = f2bf(v.x); o.y = f2bf(v.y); o.z = f2bf(v.z); o.w = f2bf(v.w);
  dst[i] = o;
}

// ---------------- rope table (exact reference gather semantics) ----------------
__global__ void k_rope_table(float2* __restrict__ tab) {
  int t = blockIdx.x * blockDim.x + threadIdx.x;   // < 65536
  int p = t >> 5, j = t & 31;
  double fp = (double)p;
  double c, s;
  if (j < 16) {
    s = sin(fp * pow(10000.0, -(2.0 * j) / 32.0));
    c = sin(fp * pow(10000.0, -(2.0 * j + 1.0) / 32.0));
  } else {
    s = cos(fp * pow(10000.0, -(2.0 * j - 32.0) / 32.0));
    c = cos(fp * pow(10000.0, -(2.0 * j - 31.0) / 32.0));
  }
  tab[p * 32 + j] = make_float2((float)c, (float)s);
}

// ---------------- QKV GEMM: 256x192 tile, 8 waves, counted-vmcnt -----------
// Full-grid 256-class tile (R12 proved +22%/CU at BN=256 but 75% grid; BN=192
// over the CONCATENATED [3072][1024] weight matrix gives 16x16 = 256 blocks
// = exactly 1/CU). Wave grid 2Mx4N; per-wave 128x48 (acc[8][3]).
// LDS 112KB: A in K-halves (dbuf, 64KB), B full-K (dbuf, 48KB) -> 1 block/CU.
// Per-thread issue order per tile: [B:3, A0:2, A1:2]. Phases:
//  Ph1: vmcnt(2)[B(t),A0(t) landed; A1(t) in flight] bar | issue B(t+1),
//       A0(t+1) | read B kk0 + A0 frags | 24 MFMA
//  Ph2: vmcnt(5)[A1(t) landed; B(t+1)+A0(t+1) in flight] bar | issue A1(t+1)
//       | read B kk1 + A1 frags | 24 MFMA
// vmcnt(0) only at final Ph2; loads never drain mid-loop. Swizzles (proven
// 0-conflict): B 128B rows sl^(row&7); A 64B rows sl^((row>>1)&3).
// Epilogue: wi = gcol>>10 per 16-col fragment (never straddles: 1024%16==0);
// wi 0/1 -> RoPE to q_r/k_r, wi 2 -> V-transpose to vt.
// Grid 256, XCD decode: x=id&7 owns m-rows {2x,2x+1} (A panels L2-resident).
__global__ __launch_bounds__(512) void k_qkv(
    const u16* __restrict__ A, const u16* __restrict__ W,
    u16* __restrict__ Oq, u16* __restrict__ Ok, u16* __restrict__ Ov,
    const float2* __restrict__ tab) {
  __shared__ __align__(16) u16 Alds[2][2][256 * 32];
  __shared__ __align__(16) u16 Blds[2][192 * 64];

  int tid = threadIdx.x;
  int lane = tid & 63, wave = tid >> 6;
  int id = blockIdx.x;
  int x = id & 7, g = id >> 3;
  int mt = 2 * x + (g & 1);
  int nt = g >> 1;
  int m0 = mt * 256;
  int n0 = nt * 192;
  int wm = wave >> 2, wn = wave & 3;
  int lg = lane >> 4, lr = lane & 15;

  f32x4 acc[8][3];
  const f32x4 vz = {0.f, 0.f, 0.f, 0.f};
#pragma unroll
  for (int i = 0; i < 8; ++i)
#pragma unroll
    for (int j = 0; j < 3; ++j) acc[i][j] = vz;

  // B full-K stage: 3 chunks/thread (1536 chunks = 192 rows x 64 cols)
  auto SB = [&](int t_, int d_) {
#pragma unroll
    for (int it = 0; it < 3; ++it) {
      int c = it * 512 + tid;
      int row = c >> 3, sl = c & 7;
      int cw = sl ^ (row & 7);         // pre-swizzled source
      gload16(&W[(size_t)(n0 + row) * HID_ + t_ * 64 + cw * 8],
              &Blds[d_][(it * 512 + wave * 64) * 8]);
    }
  };
  // A K-half stage: 2 chunks/thread (1024 chunks = 256 rows x 32 cols)
  auto SA = [&](int t_, int d_, int hk_) {
#pragma unroll
    for (int it = 0; it < 2; ++it) {
      int c = it * 512 + tid;
      int row = c >> 2, sl = c & 3;
      int cw = sl ^ ((row >> 1) & 3);
      gload16(&A[(size_t)(m0 + row) * HID_ + t_ * 64 + hk_ * 32 + cw * 8],
              &Alds[d_][hk_][(it * 512 + wave * 64) * 8]);
    }
  };

  // prologue: tile 0 in issue order B, A0, A1 (7 loads/thread)
  SB(0, 0); SA(0, 0, 0); SA(0, 0, 1);

  for (int t = 0; t < 16; ++t) {
    int cur = t & 1, nxt = cur ^ 1;
    bool more = (t < 15);
    bf16x8 bfr[3], afr[8];

    // ---------------- Ph1 (K-half 0) ----------------
    asm volatile("s_waitcnt vmcnt(2)" ::: "memory");   // B(t),A0(t) landed
    __builtin_amdgcn_s_barrier();
    __builtin_amdgcn_sched_barrier(0);
    if (more) { SB(t + 1, nxt); SA(t + 1, nxt, 0); }
#pragma unroll
    for (int ni = 0; ni < 3; ++ni) {
      int row = wn * 48 + ni * 16 + lr;
      int ci = lg ^ (row & 7);
      bfr[ni] = *(const bf16x8*)&Blds[cur][row * 64 + ci * 8];
    }
#pragma unroll
    for (int mi = 0; mi < 8; ++mi) {
      int row = wm * 128 + mi * 16 + lr;
      int ci = lg ^ ((row >> 1) & 3);
      afr[mi] = *(const bf16x8*)&Alds[cur][0][row * 32 + ci * 8];
    }
    __builtin_amdgcn_s_setprio(1);
#pragma unroll
    for (int mi = 0; mi < 8; ++mi)
#pragma unroll
      for (int ni = 0; ni < 3; ++ni)
        acc[mi][ni] = __builtin_amdgcn_mfma_f32_16x16x32_bf16(afr[mi], bfr[ni], acc[mi][ni], 0, 0, 0);
    __builtin_amdgcn_s_setprio(0);

    // ---------------- Ph2 (K-half 1) ----------------
    if (more) { asm volatile("s_waitcnt vmcnt(5)" ::: "memory"); }   // A1(t) landed
    else      { asm volatile("s_waitcnt vmcnt(0)" ::: "memory"); }
    __builtin_amdgcn_s_barrier();
    __builtin_amdgcn_sched_barrier(0);
    if (more) SA(t + 1, nxt, 1);
#pragma unroll
    for (int ni = 0; ni < 3; ++ni) {
      int row = wn * 48 + ni * 16 + lr;
      int ci = (4 + lg) ^ (row & 7);
      bfr[ni] = *(const bf16x8*)&Blds[cur][row * 64 + ci * 8];
    }
#pragma unroll
    for (int mi = 0; mi < 8; ++mi) {
      int row = wm * 128 + mi * 16 + lr;
      int ci = lg ^ ((row >> 1) & 3);
      afr[mi] = *(const bf16x8*)&Alds[cur][1][row * 32 + ci * 8];
    }
    __builtin_amdgcn_s_setprio(1);
#pragma unroll
    for (int mi = 0; mi < 8; ++mi)
#pragma unroll
      for (int ni = 0; ni < 3; ++ni)
        acc[mi][ni] = __builtin_amdgcn_mfma_f32_16x16x32_bf16(afr[mi], bfr[ni], acc[mi][ni], 0, 0, 0);
    __builtin_amdgcn_s_setprio(0);
  }

  // ---------------- epilogues (per-wave 128x48 at (wm*128, wn*48)) --------
#pragma unroll
  for (int ni = 0; ni < 3; ++ni) {
    int gcol = n0 + wn * 48 + ni * 16 + lr;
    int wi = gcol >> 10;               // wave-uniform per fragment
    if (wi == 2) {
      // V: write transposed vt[((b*16+h)*64 + d)*2048 + s]
      int vcol = gcol & 1023;
      int h = vcol >> 6, dd = vcol & 63;
#pragma unroll
      for (int mi = 0; mi < 8; ++mi) {
        int grow0 = m0 + wm * 128 + mi * 16 + lg * 4;
        int bb = grow0 >> 11;
        int s = grow0 & 2047;
        u64 pk = (u64)f2bf(acc[mi][ni][0]) |
                 ((u64)f2bf(acc[mi][ni][1]) << 16) |
                 ((u64)f2bf(acc[mi][ni][2]) << 32) |
                 ((u64)f2bf(acc[mi][ni][3]) << 48);
        *(u64*)&Ov[((size_t)(bb * NH_ + h) * HD_ + dd) * S_ + s] = pk;
      }
    } else {
      // Q / K: RoPE. Pair (2j,2j+1) lives in lanes (lr even, lr odd).
      u16* OB = wi ? Ok : Oq;
      float sc = wi ? 1.0f : QSCALE;
      int col = gcol & 1023;
      int h = col >> 6;
      int j = (col & 63) >> 1;
      bool even = !(gcol & 1);
      int ocol = h * 64 + (even ? j : 32 + j);
#pragma unroll
      for (int mi = 0; mi < 8; ++mi) {
#pragma unroll
        for (int r = 0; r < 4; ++r) {
          float val = acc[mi][ni][r];
          float pv = __shfl_xor(val, 1);
          int grow = m0 + wm * 128 + mi * 16 + lg * 4 + r;
          int s = grow & 2047;
          float2 cs = tab[s * 32 + j];
          float xe = even ? val : pv;
          float xo = even ? pv : val;
          float res = even ? (xe * cs.x - xo * cs.y) : (xe * cs.y + xo * cs.x);
          OB[(size_t)grow * 1024 + ocol] = f2bf(res * sc);
        }
      }
    }
  }
}

// ---------------- O-projection GEMM: 64x128 tile, 8 waves, 1-barrier dbuf --
__global__ __launch_bounds__(512) void k_oproj(
    const u16* __restrict__ A, const u16* __restrict__ W0,
    float* __restrict__ OF, int K) {
  __shared__ __align__(16) u16 Al[2][64 * 64];
  __shared__ __align__(16) u16 Bl[2][128 * 64];

  int tid = threadIdx.x;
  int lane = tid & 63, wave = tid >> 6;
  int m0 = blockIdx.y * 64;
  int n0 = blockIdx.x * 128;
  int wm = wave >> 1, wn = wave & 1;
  int lg = lane >> 4, lr = lane & 15;

  f32x4 acc[4];
  const f32x4 vz = {0.f, 0.f, 0.f, 0.f};
#pragma unroll
  for (int j = 0; j < 4; ++j) acc[j] = vz;

  auto STAGE = [&](int t_, int bs_) {
    int k0 = t_ * 64;
    {
      int c = tid;
      int row = c >> 3;
      int cw = (c & 7) ^ (row & 7);
      gload16(&A[(size_t)(m0 + row) * K + k0 + cw * 8], &Al[bs_][(wave * 64) * 8]);
    }
#pragma unroll
    for (int it = 0; it < 2; ++it) {
      int c = it * 512 + tid;
      int row = c >> 3;
      int cw = (c & 7) ^ (row & 7);
      gload16(&W0[(size_t)(n0 + row) * K + k0 + cw * 8], &Bl[bs_][(it * 512 + wave * 64) * 8]);
    }
  };

  int nkt = K >> 6;
  STAGE(0, 0);

  for (int t = 0; t < nkt; ++t) {
    int cur = t & 1;
    asm volatile("s_waitcnt vmcnt(0)" ::: "memory");
    __builtin_amdgcn_s_barrier();
    __builtin_amdgcn_sched_barrier(0);
    if (t + 1 < nkt) STAGE(t + 1, cur ^ 1);

#pragma unroll
    for (int kk = 0; kk < 2; ++kk) {
      bf16x8 af, bfr[4];
      {
        int row = wm * 16 + lr;
        int ci = (kk * 4 + lg) ^ (row & 7);
        af = *(const bf16x8*)&Al[cur][row * 64 + ci * 8];
      }
#pragma unroll
      for (int ni = 0; ni < 4; ++ni) {
        int row = wn * 64 + ni * 16 + lr;
        int ci = (kk * 4 + lg) ^ (row & 7);
        bfr[ni] = *(const bf16x8*)&Bl[cur][row * 64 + ci * 8];
      }
      __builtin_amdgcn_s_setprio(1);
#pragma unroll
      for (int ni = 0; ni < 4; ++ni)
        acc[ni] = __builtin_amdgcn_mfma_f32_16x16x32_bf16(af, bfr[ni], acc[ni], 0, 0, 0);
      __builtin_amdgcn_s_setprio(0);
    }
  }

#pragma unroll
  for (int ni = 0; ni < 4; ++ni)
#pragma unroll
    for (int r = 0; r < 4; ++r) {
      int grow = m0 + wm * 16 + lg * 4 + r;
      int gcol = n0 + wn * 64 + ni * 16 + lr;
      OF[(size_t)grow * 1024 + gcol] = acc[ni][r];
    }
}

// ---------------- flash attention v6 (round-14 proven) ---------------------
__global__ __launch_bounds__(256, 4) void k_attn(
    const u16* __restrict__ Q, const u16* __restrict__ Kr, const u16* __restrict__ VT,
    u16* __restrict__ O) {
  __shared__ __align__(16) u16 Kl[2][64 * 64];
  __shared__ __align__(16) u16 Vl[2][64 * 64];

  int tid = threadIdx.x, lane = tid & 63, wave = tid >> 6;
  int id = blockIdx.x;                 // 0..1023
  int qt = 31 - (id >> 5);             // descending work (LPT)
  int bh = id & 31;
  int b = bh >> 4, h = bh & 15;
  int lg = lane >> 4, lr = lane & 15;
  int bS = b * S_;
  int nkt = qt + 1;
  int q0 = qt * 64 + wave * 16;

  const u16* vtb = &VT[(size_t)bh * HD_ * S_];
  int l8 = lane >> 3, l7 = lane & 7;
  int sl = l7 ^ l8;   // pre-swizzled global slot

  auto STAGE = [&](int kt_, int bs_) {
#pragma unroll
    for (int it = 0; it < 2; ++it) {
      int rb = wave * 16 + it * 8;     // wave-uniform LDS row base
      int r = rb + l8;
      gload16(&Kr[(size_t)(bS + kt_ * 64 + r) * HID_ + h * HD_ + sl * 8],
              &Kl[bs_][rb * 64]);
      gload16(&vtb[(size_t)r * S_ + kt_ * 64 + sl * 8],
              &Vl[bs_][rb * 64]);
    }
  };

  STAGE(0, 0);

  bf16x8 qf[2];
#pragma unroll
  for (int kk = 0; kk < 2; ++kk)
    qf[kk] = *(const bf16x8*)
        &Q[(size_t)(bS + q0 + lr) * HID_ + h * HD_ + kk * 32 + lg * 8];

  f32x4 acc[4];
  const f32x4 vz = {0.f, 0.f, 0.f, 0.f};
#pragma unroll
  for (int df = 0; df < 4; ++df) acc[df] = vz;
  float l_ = 0.f;                      // per-lane partial sum

  for (int kt = 0; kt < nkt; ++kt) {
    int cur = kt & 1;
    if (kt + 1 < nkt) {
      STAGE(kt + 1, cur ^ 1);
      asm volatile("s_waitcnt vmcnt(4)" ::: "memory");
    } else {
      asm volatile("s_waitcnt vmcnt(0)" ::: "memory");
    }
    __builtin_amdgcn_s_barrier();
    __builtin_amdgcn_sched_barrier(0);

    // K fragments
    bf16x8 kfr[4][2];
#pragma unroll
    for (int kf = 0; kf < 4; ++kf) {
      int row = kf * 16 + lr;
#pragma unroll
      for (int kk = 0; kk < 2; ++kk) {
        int ci = (kk * 4 + lg) ^ (row & 7);
        kfr[kf][kk] = *(const bf16x8*)&Kl[cur][row * 64 + ci * 8];
      }
    }

    // QK^T (swapped): st rows = keys, cols = q
    f32x4 st[4];
#pragma unroll
    for (int kf = 0; kf < 4; ++kf) st[kf] = vz;
    __builtin_amdgcn_s_setprio(1);
#pragma unroll
    for (int kk = 0; kk < 2; ++kk)
#pragma unroll
      for (int kf = 0; kf < 4; ++kf)
        st[kf] = __builtin_amdgcn_mfma_f32_16x16x32_bf16(
            kfr[kf][kk], qf[kk], st[kf], 0, 0, 0);
    __builtin_amdgcn_s_setprio(0);

    if (kt == qt) {   // diagonal tile: causal mask
      int qg = q0 + lr;
#pragma unroll
      for (int kf = 0; kf < 4; ++kf)
#pragma unroll
        for (int r = 0; r < 4; ++r) {
          int kg = kt * 64 + kf * 16 + lg * 4 + r;
          if (kg > qg) st[kf][r] = -1e30f;
        }
    }

    // static-max softmax: P = exp2(st - MBIAS); no reductions, no rescale
    float ts = 0.f;
    bf16x4 pb[4];
#pragma unroll
    for (int kf = 0; kf < 4; ++kf) {
#pragma unroll
      for (int r = 0; r < 4; ++r) {
        float e = __builtin_amdgcn_exp2f(st[kf][r] - MBIAS);
        st[kf][r] = e;
        ts += e;
      }
      u32 w0, w1;
      asm("v_cvt_pk_bf16_f32 %0, %1, %2" : "=v"(w0) : "v"(st[kf][0]), "v"(st[kf][1]));
      asm("v_cvt_pk_bf16_f32 %0, %1, %2" : "=v"(w1) : "v"(st[kf][2]), "v"(st[kf][3]));
      union { u32 u[2]; bf16x4 v; } pk;
      pk.u[0] = w0; pk.u[1] = w1;
      pb[kf] = pk.v;
    }
    l_ += ts;

    // PV: O^T += V^T . P^T
    __builtin_amdgcn_s_setprio(1);
#pragma unroll
    for (int df = 0; df < 4; ++df) {
      int row = df * 16 + lr;
#pragma unroll
      for (int kf = 0; kf < 4; ++kf) {
        int slot = (kf * 2 + (lg >> 1)) ^ (row & 7);
        bf16x4 vfr = *(const bf16x4*)&Vl[cur][row * 64 + slot * 8 + (lg & 1) * 4];
        acc[df] = __builtin_amdgcn_mfma_f32_16x16x16bf16_1k(
            vfr, pb[kf], acc[df], 0, 0, 0);
      }
    }
    __builtin_amdgcn_s_setprio(0);

    __builtin_amdgcn_sched_barrier(0);
    __builtin_amdgcn_s_barrier();
  }

  // epilogue: reduce l across the 4 lane-groups once, then O = acc / l
  l_ += __shfl_xor(l_, 16);
  l_ += __shfl_xor(l_, 32);
  float inv = 1.0f / l_;
  int grow = bS + q0 + lr;
#pragma unroll
  for (int df = 0; df < 4; ++df) {
    u64 pk = (u64)f2bf(acc[df][0] * inv) |
             ((u64)f2bf(acc[df][1] * inv) << 16) |
             ((u64)f2bf(acc[df][2] * inv) << 32) |
             ((u64)f2bf(acc[df][3] * inv) << 48);
    *(u64*)&O[(size_t)grow * HID_ + h * HD_ + df * 16 + lg * 4] = pk;
  }
}

// ---------------- launch ----------------
extern "C" void kernel_launch(void* const* d_in, const int* in_sizes, int n_in,
                              void* d_out, int out_size, void* d_ws, size_t ws_size,
                              hipStream_t stream) {
  const float* hs = (const float*)d_in[0];
  const float* wq = (const float*)d_in[2];
  const float* wk = (const float*)d_in[3];
  const float* wv = (const float*)d_in[4];
  const float* wo = (const float*)d_in[5];
  float* out = (float*)d_out;

  char* ws = (char*)d_ws;
  const size_t P = (size_t)MR_ * HID_ * 2;   // 8 MiB plane
  u16* Xb  = (u16*)(ws);                     // plane 0; reused as attn_o
  u16* Wcat = (u16*)(ws + P);                // [wq|wk|wv|wo] contiguous rows
  u16* Wob = (u16*)(ws + P + (size_t)HID_ * HID_ * 6);
  u16* q_r = (u16*)(ws + 2 * P);
  u16* k_r = (u16*)(ws + 3 * P);
  u16* vt  = (u16*)(ws + 4 * P);
  float2* tab = (float2*)(ws + 5 * P);
  u16* attn_o = Xb;

  // converts + rope table
  k_cvt_all<<<8192, 256, 0, stream>>>(hs, wq, wk, wv, wo, (ushort4*)ws);
  k_rope_table<<<256, 256, 0, stream>>>(tab);

  // QKV projections (256x192 full-grid tile) + fused RoPE / V-transpose
  k_qkv<<<256, 512, 0, stream>>>(Xb, Wcat, q_r, k_r, vt, tab);

  // attention (LPT-ordered triangular blocks, static-max softmax)
  k_attn<<<1024, 256, 0, stream>>>(q_r, k_r, vt, attn_o);

  // output projection -> f32
  k_oproj<<<dim3(8, 64), 512, 0, stream>>>(attn_o, Wob, out, HID_);
}

// Round 19
// 109.612 us; speedup vs baseline: 1.1155x; 1.0174x over previous
//
#include <hip/hip_runtime.h>
#include <hip/hip_bf16.h>
#include <math.h>

typedef unsigned short u16;
typedef unsigned int   u32;
typedef unsigned long long u64;
typedef __attribute__((ext_vector_type(8))) short bf16x8;
typedef __attribute__((ext_vector_type(4))) short bf16x4;
typedef __attribute__((ext_vector_type(4))) float f32x4;

#define B_   2
#define S_   2048
#define HID_ 1024
#define NH_  16
#define HD_  64
#define MR_  (B_*S_)   // 4096 rows

// 0.125 * log2(e) : folds the 1/sqrt(64) score scale and exp->exp2 into Q.
#define QSCALE 0.1803368801111137f
// Static softmax bias (log2 domain); see round-9 analysis.
#define MBIAS 32.0f

__device__ __forceinline__ u16 f2bf(float f) {
  union { float f; u32 u; } x; x.f = f;
  u32 r = x.u + 0x7fffu + ((x.u >> 16) & 1u);
  return (u16)(r >> 16);
}
__device__ __forceinline__ void gload16(const void* g, void* l) {
  __builtin_amdgcn_global_load_lds(
      (const __attribute__((address_space(1))) u32*)g,
      (__attribute__((address_space(3))) u32*)l, 16, 0, 0);
}

// ---------------- fused f32 -> bf16 convert (hs + 4 weights) ----------------
// NOTE: weights land CONTIGUOUSLY at ws+P: [wq(1024) | wk(1024) | wv(1024) |
// wo(1024)] rows -> k_qkv treats rows 0..3071 as one concatenated B matrix.
__global__ void k_cvt_all(const float* __restrict__ hs, const float* __restrict__ wq,
                          const float* __restrict__ wk, const float* __restrict__ wv,
                          const float* __restrict__ wo, ushort4* __restrict__ dst) {
  int i = blockIdx.x * blockDim.x + threadIdx.x;   // < 2097152
  const float4* src;
  int idx;
  if (i < 1048576) {
    src = (const float4*)hs; idx = i;
  } else {
    int j = i - 1048576;
    int w = j >> 18; idx = j & 262143;
    src = (const float4*)(w == 0 ? wq : w == 1 ? wk : w == 2 ? wv : wo);
  }
  float4 v = src[idx];
  ushort4 o;
  o.x = f2bf(v.x); o.y = f2bf(v.y); o.z = f2bf(v.z); o.w = f2bf(v.w);
  dst[i] = o;
}

// ---------------- rope table (exact reference gather semantics) ----------------
__global__ void k_rope_table(float2* __restrict__ tab) {
  int t = blockIdx.x * blockDim.x + threadIdx.x;   // < 65536
  int p = t >> 5, j = t & 31;
  double fp = (double)p;
  double c, s;
  if (j < 16) {
    s = sin(fp * pow(10000.0, -(2.0 * j) / 32.0));
    c = sin(fp * pow(10000.0, -(2.0 * j + 1.0) / 32.0));
  } else {
    s = cos(fp * pow(10000.0, -(2.0 * j - 32.0) / 32.0));
    c = cos(fp * pow(10000.0, -(2.0 * j - 31.0) / 32.0));
  }
  tab[p * 32 + j] = make_float2((float)c, (float)s);
}

// ---------------- QKV GEMM: 256x192 tile, 8 waves, counted-vmcnt -----------
// (Round-18 proven: 45.7us, FETCH 29MB.) BN=192 over the CONCATENATED
// [3072][1024] weight matrix -> 16x16 = 256 blocks = 1/CU. Wave grid 2Mx4N;
// per-wave 128x48 (acc[8][3]). LDS 112KB: A in K-halves (dbuf), B full-K
// (dbuf). Per-thread issue order per tile: [B:3, A0:2, A1:2]. Phases:
//  Ph1: vmcnt(2) bar | issue B(t+1),A0(t+1) | read B kk0 + A0 | 24 MFMA
//  Ph2: vmcnt(5) bar | issue A1(t+1)        | read B kk1 + A1 | 24 MFMA
// vmcnt(0) only at final Ph2. Swizzles: B sl^(row&7); A sl^((row>>1)&3).
// Grid 256, XCD decode: x=id&7 owns m-rows {2x,2x+1}.
__global__ __launch_bounds__(512) void k_qkv(
    const u16* __restrict__ A, const u16* __restrict__ W,
    u16* __restrict__ Oq, u16* __restrict__ Ok, u16* __restrict__ Ov,
    const float2* __restrict__ tab) {
  __shared__ __align__(16) u16 Alds[2][2][256 * 32];
  __shared__ __align__(16) u16 Blds[2][192 * 64];

  int tid = threadIdx.x;
  int lane = tid & 63, wave = tid >> 6;
  int id = blockIdx.x;
  int x = id & 7, g = id >> 3;
  int mt = 2 * x + (g & 1);
  int nt = g >> 1;
  int m0 = mt * 256;
  int n0 = nt * 192;
  int wm = wave >> 2, wn = wave & 3;
  int lg = lane >> 4, lr = lane & 15;

  f32x4 acc[8][3];
  const f32x4 vz = {0.f, 0.f, 0.f, 0.f};
#pragma unroll
  for (int i = 0; i < 8; ++i)
#pragma unroll
    for (int j = 0; j < 3; ++j) acc[i][j] = vz;

  auto SB = [&](int t_, int d_) {
#pragma unroll
    for (int it = 0; it < 3; ++it) {
      int c = it * 512 + tid;
      int row = c >> 3, sl = c & 7;
      int cw = sl ^ (row & 7);
      gload16(&W[(size_t)(n0 + row) * HID_ + t_ * 64 + cw * 8],
              &Blds[d_][(it * 512 + wave * 64) * 8]);
    }
  };
  auto SA = [&](int t_, int d_, int hk_) {
#pragma unroll
    for (int it = 0; it < 2; ++it) {
      int c = it * 512 + tid;
      int row = c >> 2, sl = c & 3;
      int cw = sl ^ ((row >> 1) & 3);
      gload16(&A[(size_t)(m0 + row) * HID_ + t_ * 64 + hk_ * 32 + cw * 8],
              &Alds[d_][hk_][(it * 512 + wave * 64) * 8]);
    }
  };

  SB(0, 0); SA(0, 0, 0); SA(0, 0, 1);

  for (int t = 0; t < 16; ++t) {
    int cur = t & 1, nxt = cur ^ 1;
    bool more = (t < 15);
    bf16x8 bfr[3], afr[8];

    // ---------------- Ph1 (K-half 0) ----------------
    asm volatile("s_waitcnt vmcnt(2)" ::: "memory");
    __builtin_amdgcn_s_barrier();
    __builtin_amdgcn_sched_barrier(0);
    if (more) { SB(t + 1, nxt); SA(t + 1, nxt, 0); }
#pragma unroll
    for (int ni = 0; ni < 3; ++ni) {
      int row = wn * 48 + ni * 16 + lr;
      int ci = lg ^ (row & 7);
      bfr[ni] = *(const bf16x8*)&Blds[cur][row * 64 + ci * 8];
    }
#pragma unroll
    for (int mi = 0; mi < 8; ++mi) {
      int row = wm * 128 + mi * 16 + lr;
      int ci = lg ^ ((row >> 1) & 3);
      afr[mi] = *(const bf16x8*)&Alds[cur][0][row * 32 + ci * 8];
    }
    __builtin_amdgcn_s_setprio(1);
#pragma unroll
    for (int mi = 0; mi < 8; ++mi)
#pragma unroll
      for (int ni = 0; ni < 3; ++ni)
        acc[mi][ni] = __builtin_amdgcn_mfma_f32_16x16x32_bf16(afr[mi], bfr[ni], acc[mi][ni], 0, 0, 0);
    __builtin_amdgcn_s_setprio(0);

    // ---------------- Ph2 (K-half 1) ----------------
    if (more) { asm volatile("s_waitcnt vmcnt(5)" ::: "memory"); }
    else      { asm volatile("s_waitcnt vmcnt(0)" ::: "memory"); }
    __builtin_amdgcn_s_barrier();
    __builtin_amdgcn_sched_barrier(0);
    if (more) SA(t + 1, nxt, 1);
#pragma unroll
    for (int ni = 0; ni < 3; ++ni) {
      int row = wn * 48 + ni * 16 + lr;
      int ci = (4 + lg) ^ (row & 7);
      bfr[ni] = *(const bf16x8*)&Blds[cur][row * 64 + ci * 8];
    }
#pragma unroll
    for (int mi = 0; mi < 8; ++mi) {
      int row = wm * 128 + mi * 16 + lr;
      int ci = lg ^ ((row >> 1) & 3);
      afr[mi] = *(const bf16x8*)&Alds[cur][1][row * 32 + ci * 8];
    }
    __builtin_amdgcn_s_setprio(1);
#pragma unroll
    for (int mi = 0; mi < 8; ++mi)
#pragma unroll
      for (int ni = 0; ni < 3; ++ni)
        acc[mi][ni] = __builtin_amdgcn_mfma_f32_16x16x32_bf16(afr[mi], bfr[ni], acc[mi][ni], 0, 0, 0);
    __builtin_amdgcn_s_setprio(0);
  }

  // ---------------- epilogues (per-wave 128x48 at (wm*128, wn*48)) --------
#pragma unroll
  for (int ni = 0; ni < 3; ++ni) {
    int gcol = n0 + wn * 48 + ni * 16 + lr;
    int wi = gcol >> 10;               // wave-uniform per fragment
    if (wi == 2) {
      int vcol = gcol & 1023;
      int h = vcol >> 6, dd = vcol & 63;
#pragma unroll
      for (int mi = 0; mi < 8; ++mi) {
        int grow0 = m0 + wm * 128 + mi * 16 + lg * 4;
        int bb = grow0 >> 11;
        int s = grow0 & 2047;
        u64 pk = (u64)f2bf(acc[mi][ni][0]) |
                 ((u64)f2bf(acc[mi][ni][1]) << 16) |
                 ((u64)f2bf(acc[mi][ni][2]) << 32) |
                 ((u64)f2bf(acc[mi][ni][3]) << 48);
        *(u64*)&Ov[((size_t)(bb * NH_ + h) * HD_ + dd) * S_ + s] = pk;
      }
    } else {
      u16* OB = wi ? Ok : Oq;
      float sc = wi ? 1.0f : QSCALE;
      int col = gcol & 1023;
      int h = col >> 6;
      int j = (col & 63) >> 1;
      bool even = !(gcol & 1);
      int ocol = h * 64 + (even ? j : 32 + j);
#pragma unroll
      for (int mi = 0; mi < 8; ++mi) {
#pragma unroll
        for (int r = 0; r < 4; ++r) {
          float val = acc[mi][ni][r];
          float pv = __shfl_xor(val, 1);
          int grow = m0 + wm * 128 + mi * 16 + lg * 4 + r;
          int s = grow & 2047;
          float2 cs = tab[s * 32 + j];
          float xe = even ? val : pv;
          float xo = even ? pv : val;
          float res = even ? (xe * cs.x - xo * cs.y) : (xe * cs.y + xo * cs.x);
          OB[(size_t)grow * 1024 + ocol] = f2bf(res * sc);
        }
      }
    }
  }
}

// ---------------- O-projection GEMM: 64x128 tile, 8 waves, 1-barrier dbuf --
__global__ __launch_bounds__(512) void k_oproj(
    const u16* __restrict__ A, const u16* __restrict__ W0,
    float* __restrict__ OF, int K) {
  __shared__ __align__(16) u16 Al[2][64 * 64];
  __shared__ __align__(16) u16 Bl[2][128 * 64];

  int tid = threadIdx.x;
  int lane = tid & 63, wave = tid >> 6;
  int m0 = blockIdx.y * 64;
  int n0 = blockIdx.x * 128;
  int wm = wave >> 1, wn = wave & 1;
  int lg = lane >> 4, lr = lane & 15;

  f32x4 acc[4];
  const f32x4 vz = {0.f, 0.f, 0.f, 0.f};
#pragma unroll
  for (int j = 0; j < 4; ++j) acc[j] = vz;

  auto STAGE = [&](int t_, int bs_) {
    int k0 = t_ * 64;
    {
      int c = tid;
      int row = c >> 3;
      int cw = (c & 7) ^ (row & 7);
      gload16(&A[(size_t)(m0 + row) * K + k0 + cw * 8], &Al[bs_][(wave * 64) * 8]);
    }
#pragma unroll
    for (int it = 0; it < 2; ++it) {
      int c = it * 512 + tid;
      int row = c >> 3;
      int cw = (c & 7) ^ (row & 7);
      gload16(&W0[(size_t)(n0 + row) * K + k0 + cw * 8], &Bl[bs_][(it * 512 + wave * 64) * 8]);
    }
  };

  int nkt = K >> 6;
  STAGE(0, 0);

  for (int t = 0; t < nkt; ++t) {
    int cur = t & 1;
    asm volatile("s_waitcnt vmcnt(0)" ::: "memory");
    __builtin_amdgcn_s_barrier();
    __builtin_amdgcn_sched_barrier(0);
    if (t + 1 < nkt) STAGE(t + 1, cur ^ 1);

#pragma unroll
    for (int kk = 0; kk < 2; ++kk) {
      bf16x8 af, bfr[4];
      {
        int row = wm * 16 + lr;
        int ci = (kk * 4 + lg) ^ (row & 7);
        af = *(const bf16x8*)&Al[cur][row * 64 + ci * 8];
      }
#pragma unroll
      for (int ni = 0; ni < 4; ++ni) {
        int row = wn * 64 + ni * 16 + lr;
        int ci = (kk * 4 + lg) ^ (row & 7);
        bfr[ni] = *(const bf16x8*)&Bl[cur][row * 64 + ci * 8];
      }
      __builtin_amdgcn_s_setprio(1);
#pragma unroll
      for (int ni = 0; ni < 4; ++ni)
        acc[ni] = __builtin_amdgcn_mfma_f32_16x16x32_bf16(af, bfr[ni], acc[ni], 0, 0, 0);
      __builtin_amdgcn_s_setprio(0);
    }
  }

#pragma unroll
  for (int ni = 0; ni < 4; ++ni)
#pragma unroll
    for (int r = 0; r < 4; ++r) {
      int grow = m0 + wm * 16 + lg * 4 + r;
      int gcol = n0 + wn * 64 + ni * 16 + lr;
      OF[(size_t)grow * 1024 + gcol] = acc[ni][r];
    }
}

// ---------------- flash attention v8: KVBLK=128 ----------------------------
// One 64-row q-tile per block (4 waves x 16 rows); KVBLK=128 halves barriers,
// waits and loop overhead per key vs v6. nkt = qt/2+1 (LPT preserved).
// LDS 64KB (K 128x64 + V^T 64x128, dbuf) -> 2 blocks/CU. STAGE = 8 loads;
// steady-state vmcnt(8) (tile-t landed, tile-t+1 in flight), vmcnt(0) last.
// V^T rows are 256B (16 slots); swizzle slot^(row&15) both sides -> <=2-way.
// Even-qt blocks half-mask their last tile (exp2 underflows to 0): ~3% waste.
__global__ __launch_bounds__(256, 2) void k_attn(
    const u16* __restrict__ Q, const u16* __restrict__ Kr, const u16* __restrict__ VT,
    u16* __restrict__ O) {
  __shared__ __align__(16) u16 Kl[2][128 * 64];
  __shared__ __align__(16) u16 Vl[2][64 * 128];

  int tid = threadIdx.x, lane = tid & 63, wave = tid >> 6;
  int id = blockIdx.x;                 // 0..1023
  int qt = 31 - (id >> 5);             // descending work (LPT)
  int bh = id & 31;
  int b = bh >> 4, h = bh & 15;
  int lg = lane >> 4, lr = lane & 15;
  int bS = b * S_;
  int nkt = (qt >> 1) + 1;
  int q0 = qt * 64 + wave * 16;

  const u16* vtb = &VT[(size_t)bh * HD_ * S_];
  int l8 = lane >> 3, l7 = lane & 7;
  int slk = l7 ^ l8;                   // K pre-swizzled slot (rb%8==0)
  int l16 = lane >> 4, l15 = lane & 15;

  auto STAGE = [&](int kt_, int bs_) {
    // K: 128 rows x 64 cols, 8B-slot rows; 4 loads/thread
#pragma unroll
    for (int it = 0; it < 4; ++it) {
      int rb = wave * 32 + it * 8;     // wave-uniform row base (mult of 8)
      int r = rb + l8;
      gload16(&Kr[(size_t)(bS + kt_ * 128 + r) * HID_ + h * HD_ + slk * 8],
              &Kl[bs_][rb * 64]);
    }
    // V^T: 64 rows x 128 cols, 16 slots/row; 4 loads/thread
#pragma unroll
    for (int it = 0; it < 4; ++it) {
      int rbv = wave * 16 + it * 4;    // wave-uniform row base (mult of 4)
      int rv = rbv + l16;
      int sw = l15 ^ (rv & 15);        // pre-swizzled source slot
      gload16(&vtb[(size_t)rv * S_ + kt_ * 128 + sw * 8],
              &Vl[bs_][rbv * 128]);
    }
  };

  STAGE(0, 0);

  bf16x8 qf[2];
#pragma unroll
  for (int kk = 0; kk < 2; ++kk)
    qf[kk] = *(const bf16x8*)
        &Q[(size_t)(bS + q0 + lr) * HID_ + h * HD_ + kk * 32 + lg * 8];

  f32x4 acc[4];
  const f32x4 vz = {0.f, 0.f, 0.f, 0.f};
#pragma unroll
  for (int df = 0; df < 4; ++df) acc[df] = vz;
  float l_ = 0.f;                      // per-lane partial sum

  for (int kt = 0; kt < nkt; ++kt) {
    int cur = kt & 1;
    if (kt + 1 < nkt) {
      STAGE(kt + 1, cur ^ 1);
      asm volatile("s_waitcnt vmcnt(8)" ::: "memory");
    } else {
      asm volatile("s_waitcnt vmcnt(0)" ::: "memory");
    }
    __builtin_amdgcn_s_barrier();
    __builtin_amdgcn_sched_barrier(0);

    // QK^T (swapped): st rows = keys (128), cols = q
    f32x4 st[8];
#pragma unroll
    for (int kf = 0; kf < 8; ++kf) st[kf] = vz;
    __builtin_amdgcn_s_setprio(1);
#pragma unroll
    for (int kf = 0; kf < 8; ++kf) {
      int row = kf * 16 + lr;
      int ci0 = lg ^ (row & 7);
      int ci1 = (4 + lg) ^ (row & 7);
      bf16x8 k0 = *(const bf16x8*)&Kl[cur][row * 64 + ci0 * 8];
      bf16x8 k1 = *(const bf16x8*)&Kl[cur][row * 64 + ci1 * 8];
      st[kf] = __builtin_amdgcn_mfma_f32_16x16x32_bf16(k0, qf[0], st[kf], 0, 0, 0);
      st[kf] = __builtin_amdgcn_mfma_f32_16x16x32_bf16(k1, qf[1], st[kf], 0, 0, 0);
    }
    __builtin_amdgcn_s_setprio(0);

    if (kt == nkt - 1) {   // boundary tile: causal mask
      int qg = q0 + lr;
#pragma unroll
      for (int kf = 0; kf < 8; ++kf)
#pragma unroll
        for (int r = 0; r < 4; ++r) {
          int kg = kt * 128 + kf * 16 + lg * 4 + r;
          if (kg > qg) st[kf][r] = -1e30f;
        }
    }

    // static-max softmax: P = exp2(st - MBIAS); no reductions, no rescale
    float ts = 0.f;
    bf16x4 pb[8];
#pragma unroll
    for (int kf = 0; kf < 8; ++kf) {
#pragma unroll
      for (int r = 0; r < 4; ++r) {
        float e = __builtin_amdgcn_exp2f(st[kf][r] - MBIAS);
        st[kf][r] = e;
        ts += e;
      }
      u32 w0, w1;
      asm("v_cvt_pk_bf16_f32 %0, %1, %2" : "=v"(w0) : "v"(st[kf][0]), "v"(st[kf][1]));
      asm("v_cvt_pk_bf16_f32 %0, %1, %2" : "=v"(w1) : "v"(st[kf][2]), "v"(st[kf][3]));
      union { u32 u[2]; bf16x4 v; } pk;
      pk.u[0] = w0; pk.u[1] = w1;
      pb[kf] = pk.v;
    }
    l_ += ts;

    // PV: O^T += V^T . P^T  (V rows 256B/16 slots, swizzle slot^(row&15))
    __builtin_amdgcn_s_setprio(1);
#pragma unroll
    for (int df = 0; df < 4; ++df) {
      int row = df * 16 + lr;
#pragma unroll
      for (int kf = 0; kf < 8; ++kf) {
        int slot = (2 * kf + (lg >> 1)) ^ (row & 15);
        bf16x4 vfr = *(const bf16x4*)&Vl[cur][row * 128 + slot * 8 + (lg & 1) * 4];
        acc[df] = __builtin_amdgcn_mfma_f32_16x16x16bf16_1k(
            vfr, pb[kf], acc[df], 0, 0, 0);
      }
    }
    __builtin_amdgcn_s_setprio(0);

    __builtin_amdgcn_sched_barrier(0);
    __builtin_amdgcn_s_barrier();
  }

  // epilogue: reduce l across the 4 lane-groups once, then O = acc / l
  l_ += __shfl_xor(l_, 16);
  l_ += __shfl_xor(l_, 32);
  float inv = 1.0f / l_;
  int grow = bS + q0 + lr;
#pragma unroll
  for (int df = 0; df < 4; ++df) {
    u64 pk = (u64)f2bf(acc[df][0] * inv) |
             ((u64)f2bf(acc[df][1] * inv) << 16) |
             ((u64)f2bf(acc[df][2] * inv) << 32) |
             ((u64)f2bf(acc[df][3] * inv) << 48);
    *(u64*)&O[(size_t)grow * HID_ + h * HD_ + df * 16 + lg * 4] = pk;
  }
}

// ---------------- launch ----------------
extern "C" void kernel_launch(void* const* d_in, const int* in_sizes, int n_in,
                              void* d_out, int out_size, void* d_ws, size_t ws_size,
                              hipStream_t stream) {
  const float* hs = (const float*)d_in[0];
  const float* wq = (const float*)d_in[2];
  const float* wk = (const float*)d_in[3];
  const float* wv = (const float*)d_in[4];
  const float* wo = (const float*)d_in[5];
  float* out = (float*)d_out;

  char* ws = (char*)d_ws;
  const size_t P = (size_t)MR_ * HID_ * 2;   // 8 MiB plane
  u16* Xb  = (u16*)(ws);                     // plane 0; reused as attn_o
  u16* Wcat = (u16*)(ws + P);                // [wq|wk|wv|wo] contiguous rows
  u16* Wob = (u16*)(ws + P + (size_t)HID_ * HID_ * 6);
  u16* q_r = (u16*)(ws + 2 * P);
  u16* k_r = (u16*)(ws + 3 * P);
  u16* vt  = (u16*)(ws + 4 * P);
  float2* tab = (float2*)(ws + 5 * P);
  u16* attn_o = Xb;

  // converts + rope table
  k_cvt_all<<<8192, 256, 0, stream>>>(hs, wq, wk, wv, wo, (ushort4*)ws);
  k_rope_table<<<256, 256, 0, stream>>>(tab);

  // QKV projections (256x192 full-grid tile) + fused RoPE / V-transpose
  k_qkv<<<256, 512, 0, stream>>>(Xb, Wcat, q_r, k_r, vt, tab);

  // attention (LPT-ordered triangular blocks, KVBLK=128, static-max softmax)
  k_attn<<<1024, 256, 0, stream>>>(q_r, k_r, vt, attn_o);

  // output projection -> f32
  k_oproj<<<dim3(8, 64), 512, 0, stream>>>(attn_o, Wob, out, HID_);
}